// Round 7
// baseline (1361.667 us; speedup 1.0000x reference)
//
#include <hip/hip_runtime.h>
#include <hip/hip_bf16.h>

// GRU forward, T=512 B=256 I=H=256 fp32 in, fp32 [B,1] out.
// v7: v6 structure, but MFMAs issued as inline asm with "v" constraints so
// the 192 weight fragments MUST live in arch VGPRs (v6 diagnosis: compiler
// split 128 arch + 128 AGPR and paid v_accvgpr_read copies per MFMA ->
// VALUBusy 39%/CU). Register diet to fit 256 unified at 2 waves/EU:
//   wf 192 + acc 24 + gi 12 + packed-bf16 h 4 + addr/misc ~20 ~= 252.
// Hazard handling (inline asm bypasses the builtin hazard recognizer):
//   - "s_nop 1" before each acc chain's first MFMA (VALU zero-init -> srcC);
//   - s_nop(7)x2 fence AFTER the MFMA block, taking accs as "+v" operands
//     (operand-dependency ordering, not "memory" — rule #18);
//   - MFMA->MFMA same-acc accumulate chains are HW-interlocked (Tensile
//     pattern), no nops needed inside a chain.
// h master packed to bf16 pairs via v_cvt_pk_bf16_f32 (RNE): frees 4 regs,
// also replaces the 4-op software rne for LDS stores. gi: 3 dwordx4 issued
// at loop top, consumed post-fence (latency hidden under ~1865cyc MFMA).

#define TT 512
#define BB 256
#define II 256
#define HH 256

#define SRZ (-1.4426950408889634f)   // -log2(e): sigmoid(a) = rcp(1+exp2(SRZ*a))
#define SN  (2.8853900817779268f)    // 2*log2(e): tanh(y) = 1-2*rcp(1+exp2(SN*y))

typedef __attribute__((ext_vector_type(8))) short short8;
typedef __attribute__((ext_vector_type(4))) float f32x4;

__device__ __forceinline__ unsigned short rne_bf16(float f) {
  union { float f; unsigned u; } v; v.f = f;
  unsigned r = v.u + 0x7FFFu + ((v.u >> 16) & 1u);
  return (unsigned short)(r >> 16);
}
__device__ __forceinline__ float bf2f(unsigned short b) {
  union { unsigned u; float f; } v; v.u = ((unsigned)b) << 16;
  return v.f;
}
__device__ __forceinline__ float blo(unsigned p) {
  union { unsigned u; float f; } v; v.u = p << 16; return v.f;
}
__device__ __forceinline__ float bhi(unsigned p) {
  union { unsigned u; float f; } v; v.u = p & 0xffff0000u; return v.f;
}
__device__ __forceinline__ float sigm(float x) { return 1.0f / (1.0f + __expf(-x)); }
__device__ __forceinline__ float tanhfast(float x) {
  return 1.0f - 2.0f / (__expf(2.0f * x) + 1.0f);
}

__device__ __forceinline__ short8 ldw8(const float* __restrict__ p) {
  float4 a = *reinterpret_cast<const float4*>(p);
  float4 b = *reinterpret_cast<const float4*>(p + 4);
  short8 r;
  r[0] = (short)rne_bf16(a.x); r[1] = (short)rne_bf16(a.y);
  r[2] = (short)rne_bf16(a.z); r[3] = (short)rne_bf16(a.w);
  r[4] = (short)rne_bf16(b.x); r[5] = (short)rne_bf16(b.y);
  r[6] = (short)rne_bf16(b.z); r[7] = (short)rne_bf16(b.w);
  return r;
}
__device__ __forceinline__ short8 ldw8s(const float* __restrict__ p, float s) {
  float4 a = *reinterpret_cast<const float4*>(p);
  float4 b = *reinterpret_cast<const float4*>(p + 4);
  short8 r;
  r[0] = (short)rne_bf16(a.x * s); r[1] = (short)rne_bf16(a.y * s);
  r[2] = (short)rne_bf16(a.z * s); r[3] = (short)rne_bf16(a.w * s);
  r[4] = (short)rne_bf16(b.x * s); r[5] = (short)rne_bf16(b.y * s);
  r[6] = (short)rne_bf16(b.z * s); r[7] = (short)rne_bf16(b.w * s);
  return r;
}

// 8-elem-granule XOR swizzle for [16][256] ushort tiles (16B reads contiguous;
// rows m, m+8 alias 2-way = free).
#define SWZ8(m, k) ((m) * 256 + ((k) ^ (((m) & 7) * 8)))
// legacy 16-granule swizzle (fallback kernel only)
#define SWZ(m, k) ((m) * 256 + ((k) ^ ((m) * 16)))

// inline-asm MFMA: forces A,B,C,D into arch VGPRs (no AGPR homing/copies).
__device__ __forceinline__ void mfma_first(f32x4& d, short8 a, short8 b) {
  asm volatile("s_nop 1\n\tv_mfma_f32_16x16x32_bf16 %0, %1, %2, %0"
               : "+v"(d) : "v"(a), "v"(b));
}
__device__ __forceinline__ void mfma_next(f32x4& d, short8 a, short8 b) {
  asm volatile("v_mfma_f32_16x16x32_bf16 %0, %1, %2, %0"
               : "+v"(d) : "v"(a), "v"(b));
}
// fence: orders subsequent VALU reads of the accs after 16 wait states.
__device__ __forceinline__ void mfma_fence6(f32x4& a0, f32x4& a1, f32x4& a2,
                                            f32x4& a3, f32x4& a4, f32x4& a5) {
  asm volatile("s_nop 7\n\ts_nop 7"
               : "+v"(a0), "+v"(a1), "+v"(a2), "+v"(a3), "+v"(a4), "+v"(a5));
}
__device__ __forceinline__ unsigned cvtpk_bf16(float lo, float hi) {
  unsigned r;
  asm("v_cvt_pk_bf16_f32 %0, %1, %2" : "=v"(r) : "v"(lo), "v"(hi));
  return r;
}

// ---------------- Phase 1: gi = scale*(x @ W_ih^T + bias) -------------------
// gi ushort layout: ((tile*8 + w)*64 + l)*24 + g*8 + ct*4 + q, tile = t*16+bx.
// r,z folded with SRZ*(bih+bhh); n folded with SN*bih.
__global__ __launch_bounds__(512)
__attribute__((amdgpu_waves_per_eu(2, 2)))
void gi_gemm8(const float* __restrict__ x, const float* __restrict__ Wih,
              const float* __restrict__ bih, const float* __restrict__ bhh,
              unsigned short* __restrict__ gi, int ntiles) {
  __shared__ __align__(16) unsigned short ax[2][4096];
  const int tid = threadIdx.x, l = tid & 63, w = tid >> 6;
  const int g4 = l >> 4, i15 = l & 15;

  short8 wf[3][2][8];
  float bs[3][2];
#pragma unroll
  for (int g = 0; g < 3; ++g)
#pragma unroll
    for (int ct = 0; ct < 2; ++ct) {
      int j = 32 * w + 16 * ct + i15;
      float s = (g == 2) ? SN : SRZ;
#pragma unroll
      for (int c = 0; c < 8; ++c)
        wf[g][ct][c] = ldw8s(Wih + (size_t)(g * 256 + j) * 256 + c * 32 + g4 * 8, s);
      bs[g][ct] = (g == 2) ? SN * bih[512 + j]
                           : SRZ * (bih[g * 256 + j] + bhh[g * 256 + j]);
    }

  auto stage = [&](int buf, int t) {
#pragma unroll
    for (int p = 0; p < 2; ++p) {
      int idx = p * 512 + tid;
      int m = idx >> 6, k0 = (idx & 63) << 2;
      float4 v = *reinterpret_cast<const float4*>(x + (size_t)t * 4096 + m * 256 + k0);
      ushort4 b;
      b.x = rne_bf16(v.x); b.y = rne_bf16(v.y);
      b.z = rne_bf16(v.z); b.w = rne_bf16(v.w);
      *reinterpret_cast<ushort4*>(&ax[buf][SWZ8(m, k0)]) = b;
    }
  };

  if (blockIdx.x >= ntiles) return;
  stage(0, blockIdx.x);
  int cur = 0;
  for (int tile = blockIdx.x; tile < ntiles; tile += 256) {
    __syncthreads();
    int tn = tile + 256;
    if (tn < ntiles) stage(cur ^ 1, tn);
    f32x4 aR[2] = {{0, 0, 0, 0}, {0, 0, 0, 0}};
    f32x4 aZ[2] = {{0, 0, 0, 0}, {0, 0, 0, 0}};
    f32x4 aN[2] = {{0, 0, 0, 0}, {0, 0, 0, 0}};
#pragma unroll
    for (int c = 0; c < 8; ++c) {
      short8 ah = *reinterpret_cast<const short8*>(&ax[cur][SWZ8(l & 15, c * 32 + g4 * 8)]);
#pragma unroll
      for (int ct = 0; ct < 2; ++ct) {
        if (c == 0) {
          mfma_first(aR[ct], ah, wf[0][ct][0]);
          mfma_first(aZ[ct], ah, wf[1][ct][0]);
          mfma_first(aN[ct], ah, wf[2][ct][0]);
        } else {
          mfma_next(aR[ct], ah, wf[0][ct][c]);
          mfma_next(aZ[ct], ah, wf[1][ct][c]);
          mfma_next(aN[ct], ah, wf[2][ct][c]);
        }
      }
    }
    mfma_fence6(aR[0], aR[1], aZ[0], aZ[1], aN[0], aN[1]);
    unsigned short* gp = gi + ((size_t)tile * 512 + (size_t)(w * 64 + l)) * 24;
    short8 oR, oZ, oN;
#pragma unroll
    for (int ct = 0; ct < 2; ++ct)
#pragma unroll
      for (int q = 0; q < 4; ++q) {
        oR[ct * 4 + q] = (short)rne_bf16(aR[ct][q] + bs[0][ct]);
        oZ[ct * 4 + q] = (short)rne_bf16(aZ[ct][q] + bs[1][ct]);
        oN[ct * 4 + q] = (short)rne_bf16(aN[ct][q] + bs[2][ct]);
      }
    *reinterpret_cast<short8*>(gp) = oR;
    *reinterpret_cast<short8*>(gp + 8) = oZ;
    *reinterpret_cast<short8*>(gp + 16) = oN;
    cur ^= 1;
  }
}

// ---------------- Phase 2: persistent GRU recurrence (v7) ----------------
__global__ __launch_bounds__(512)
__attribute__((amdgpu_waves_per_eu(2, 2)))
void gru_step7(const float* __restrict__ Whh, const float* __restrict__ bhh,
               const float* __restrict__ Wout, const float* __restrict__ bout,
               const unsigned short* __restrict__ gi, float* __restrict__ hchk,
               float* __restrict__ out, int t0, int nt) {
  __shared__ __align__(16) unsigned short hbuf[2][4096];  // 16 KB (SWZ8, dbuf)
  __shared__ float hfin[16][256];                         // 16 KB (epilogue)
  const int tid = threadIdx.x, l = tid & 63, w = tid >> 6;
  const int g4 = l >> 4, i15 = l & 15;
  const int bx = blockIdx.x, b0 = bx * 16;

  // full W_hh residency, forced arch-VGPR via asm MFMA: 192 regs/lane
  short8 wf[3][2][8];
  float cn[2];
#pragma unroll
  for (int g = 0; g < 3; ++g)
#pragma unroll
    for (int ct = 0; ct < 2; ++ct) {
      int j = 32 * w + 16 * ct + i15;
      float s = (g == 2) ? SN : SRZ;
#pragma unroll
      for (int c = 0; c < 8; ++c)
        wf[g][ct][c] = ldw8s(Whh + (size_t)(g * 256 + j) * 256 + c * 32 + g4 * 8, s);
    }
#pragma unroll
  for (int ct = 0; ct < 2; ++ct) cn[ct] = SN * bhh[512 + 32 * w + 16 * ct + i15];

  // h master: packed bf16 pairs, 4 regs. hp[ct][0]=(q0,q1), hp[ct][1]=(q2,q3)
  unsigned hp[2][2];
  if (t0 == 0) {
    hp[0][0] = hp[0][1] = hp[1][0] = hp[1][1] = 0;
    for (int i = tid; i < 4096; i += 512) hbuf[0][i] = 0;
  } else {
#pragma unroll
    for (int ct = 0; ct < 2; ++ct) {
      int j = 32 * w + 16 * ct + i15;
      float v0 = hchk[(size_t)(b0 + 4 * g4 + 0) * 256 + j];
      float v1 = hchk[(size_t)(b0 + 4 * g4 + 1) * 256 + j];
      float v2 = hchk[(size_t)(b0 + 4 * g4 + 2) * 256 + j];
      float v3 = hchk[(size_t)(b0 + 4 * g4 + 3) * 256 + j];
      hp[ct][0] = cvtpk_bf16(v0, v1);
      hp[ct][1] = cvtpk_bf16(v2, v3);
      hbuf[0][SWZ8(4 * g4 + 0, j)] = (unsigned short)hp[ct][0];
      hbuf[0][SWZ8(4 * g4 + 1, j)] = (unsigned short)(hp[ct][0] >> 16);
      hbuf[0][SWZ8(4 * g4 + 2, j)] = (unsigned short)hp[ct][1];
      hbuf[0][SWZ8(4 * g4 + 3, j)] = (unsigned short)(hp[ct][1] >> 16);
    }
  }
  // per-lane gi pointer; +196608 ushorts (=384KB) per step
  const unsigned short* gp = gi + ((size_t)(bx * 8 + w) * 64 + l) * 24;
  __syncthreads();

#pragma unroll 1
  for (int lt = 0; lt < nt; ++lt) {
    const int cur = lt & 1, nxt = cur ^ 1;
    // this step's gi: 3 dwordx4, issued now, consumed post-fence
    short8 gR = *reinterpret_cast<const short8*>(gp);
    short8 gZ = *reinterpret_cast<const short8*>(gp + 8);
    short8 gN = *reinterpret_cast<const short8*>(gp + 16);

    f32x4 aR[2] = {{0, 0, 0, 0}, {0, 0, 0, 0}};
    f32x4 aZ[2] = {{0, 0, 0, 0}, {0, 0, 0, 0}};
    f32x4 aN[2] = {{0, 0, 0, 0}, {0, 0, 0, 0}};
    const unsigned short* hb = hbuf[cur];
#pragma unroll
    for (int c = 0; c < 8; ++c) {
      short8 ah = *reinterpret_cast<const short8*>(&hb[SWZ8(l & 15, c * 32 + g4 * 8)]);
#pragma unroll
      for (int ct = 0; ct < 2; ++ct) {
        if (c == 0) {
          mfma_first(aR[ct], ah, wf[0][ct][0]);
          mfma_first(aZ[ct], ah, wf[1][ct][0]);
          mfma_first(aN[ct], ah, wf[2][ct][0]);
        } else {
          mfma_next(aR[ct], ah, wf[0][ct][c]);
          mfma_next(aZ[ct], ah, wf[1][ct][c]);
          mfma_next(aN[ct], ah, wf[2][ct][c]);
        }
      }
    }
    mfma_fence6(aR[0], aR[1], aZ[0], aZ[1], aN[0], aN[1]);

    unsigned short* hw = hbuf[nxt];
#pragma unroll
    for (int ct = 0; ct < 2; ++ct) {
      int j = 32 * w + 16 * ct + i15;
      float hq[4];
#pragma unroll
      for (int q = 0; q < 4; ++q) {
        float hold = (q & 1) ? bhi(hp[ct][q >> 1]) : blo(hp[ct][q >> 1]);
        float rr = __builtin_amdgcn_rcpf(
            1.0f + __builtin_amdgcn_exp2f(aR[ct][q] + bf2f((unsigned short)gR[ct * 4 + q])));
        float zz = __builtin_amdgcn_rcpf(
            1.0f + __builtin_amdgcn_exp2f(aZ[ct][q] + bf2f((unsigned short)gZ[ct * 4 + q])));
        float y = bf2f((unsigned short)gN[ct * 4 + q]) + rr * (aN[ct][q] + cn[ct]);
        float nn = 1.0f - 2.0f * __builtin_amdgcn_rcpf(1.0f + __builtin_amdgcn_exp2f(y));
        hq[q] = nn + zz * (hold - nn);
      }
      hp[ct][0] = cvtpk_bf16(hq[0], hq[1]);
      hp[ct][1] = cvtpk_bf16(hq[2], hq[3]);
      hw[SWZ8(4 * g4 + 0, j)] = (unsigned short)hp[ct][0];
      hw[SWZ8(4 * g4 + 1, j)] = (unsigned short)(hp[ct][0] >> 16);
      hw[SWZ8(4 * g4 + 2, j)] = (unsigned short)hp[ct][1];
      hw[SWZ8(4 * g4 + 3, j)] = (unsigned short)(hp[ct][1] >> 16);
    }
    gp += 196608;
    __syncthreads();
  }

  if (t0 + nt < TT) {
#pragma unroll
    for (int ct = 0; ct < 2; ++ct) {
      int j = 32 * w + 16 * ct + i15;
      hchk[(size_t)(b0 + 4 * g4 + 0) * 256 + j] = blo(hp[ct][0]);
      hchk[(size_t)(b0 + 4 * g4 + 1) * 256 + j] = bhi(hp[ct][0]);
      hchk[(size_t)(b0 + 4 * g4 + 2) * 256 + j] = blo(hp[ct][1]);
      hchk[(size_t)(b0 + 4 * g4 + 3) * 256 + j] = bhi(hp[ct][1]);
    }
  } else {
#pragma unroll
    for (int ct = 0; ct < 2; ++ct) {
      int j = 32 * w + 16 * ct + i15;
      hfin[4 * g4 + 0][j] = blo(hp[ct][0]);
      hfin[4 * g4 + 1][j] = bhi(hp[ct][0]);
      hfin[4 * g4 + 2][j] = blo(hp[ct][1]);
      hfin[4 * g4 + 3][j] = bhi(hp[ct][1]);
    }
    __syncthreads();
#pragma unroll
    for (int rr = 0; rr < 2; ++rr) {
      int r = 2 * w + rr;
      float s = 0.0f;
#pragma unroll
      for (int k = 0; k < 4; ++k) {
        int col = l + 64 * k;
        s += hfin[r][col] * Wout[col];
      }
#pragma unroll
      for (int off = 32; off > 0; off >>= 1) s += __shfl_xor(s, off, 64);
      if (l == 0) out[b0 + r] = sigm(s + bout[0]);
    }
  }
}

// ---------------- Fused fallback (used only if ws too small) ------------
__global__ __launch_bounds__(1024, 1) void gru_fused_legacy(
    const float* __restrict__ x, const float* __restrict__ Wih,
    const float* __restrict__ Whh, const float* __restrict__ bih,
    const float* __restrict__ bhh, const float* __restrict__ Wout,
    const float* __restrict__ bout, float* __restrict__ out) {
  __shared__ unsigned short hbuf[2][16 * 256];
  __shared__ unsigned short xbuf[2][16 * 256];
  __shared__ float hfin[16][256];
  int tid = threadIdx.x, lane = tid & 63, w = tid >> 6;
  int i15 = lane & 15, g4 = lane >> 4;
  int b0 = blockIdx.x * 16;
  int j = 16 * w + i15;

  short8 whh0[8], whh1[8], whh2[8], wih0[8], wih1[8], wih2[8];
#pragma unroll
  for (int c = 0; c < 8; ++c) {
    int ko = c * 32 + g4 * 8;
    whh0[c] = ldw8(Whh + (size_t)j * 256 + ko);
    whh1[c] = ldw8(Whh + (size_t)(256 + j) * 256 + ko);
    whh2[c] = ldw8(Whh + (size_t)(512 + j) * 256 + ko);
    wih0[c] = ldw8(Wih + (size_t)j * 256 + ko);
    wih1[c] = ldw8(Wih + (size_t)(256 + j) * 256 + ko);
    wih2[c] = ldw8(Wih + (size_t)(512 + j) * 256 + ko);
  }
  float bias_r = bih[j] + bhh[j];
  float bias_z = bih[256 + j] + bhh[256 + j];
  float bihn = bih[512 + j], bhhn = bhh[512 + j];

  f32x4 h = {0, 0, 0, 0};
  for (int idx = tid; idx < 16 * 256; idx += 1024) hbuf[0][idx] = 0;
  {
    int m = tid >> 6, k0 = (tid & 63) << 2;
    float4 v = *reinterpret_cast<const float4*>(x + (size_t)b0 * II + m * 256 + k0);
    ushort4 b;
    b.x = rne_bf16(v.x); b.y = rne_bf16(v.y);
    b.z = rne_bf16(v.z); b.w = rne_bf16(v.w);
    *reinterpret_cast<ushort4*>(&xbuf[0][SWZ(m, k0)]) = b;
  }
  __syncthreads();

  for (int lt = 0; lt < TT; ++lt) {
    int cur = lt & 1, nxt = cur ^ 1;
    short8 ah[8], axf[8];
#pragma unroll
    for (int c = 0; c < 8; ++c) {
      int m = lane & 15, k0 = c * 32 + g4 * 8;
      ah[c] = *reinterpret_cast<const short8*>(&hbuf[cur][SWZ(m, k0)]);
      axf[c] = *reinterpret_cast<const short8*>(&xbuf[cur][SWZ(m, k0)]);
    }
    f32x4 gr = {0, 0, 0, 0}, gz = {0, 0, 0, 0}, gn = {0, 0, 0, 0};
    f32x4 ar = {0, 0, 0, 0}, az = {0, 0, 0, 0}, an = {0, 0, 0, 0};
#pragma unroll
    for (int c = 0; c < 8; ++c) {
      gr = __builtin_amdgcn_mfma_f32_16x16x32_bf16(axf[c], wih0[c], gr, 0, 0, 0);
      gz = __builtin_amdgcn_mfma_f32_16x16x32_bf16(axf[c], wih1[c], gz, 0, 0, 0);
      gn = __builtin_amdgcn_mfma_f32_16x16x32_bf16(axf[c], wih2[c], gn, 0, 0, 0);
    }
    if (lt + 1 < TT) {
      int m = tid >> 6, k0 = (tid & 63) << 2;
      float4 v = *reinterpret_cast<const float4*>(
          x + ((size_t)(lt + 1) * BB + b0) * II + m * 256 + k0);
      ushort4 b;
      b.x = rne_bf16(v.x); b.y = rne_bf16(v.y);
      b.z = rne_bf16(v.z); b.w = rne_bf16(v.w);
      *reinterpret_cast<ushort4*>(&xbuf[nxt][SWZ(m, k0)]) = b;
    }
#pragma unroll
    for (int c = 0; c < 8; ++c) {
      ar = __builtin_amdgcn_mfma_f32_16x16x32_bf16(ah[c], whh0[c], ar, 0, 0, 0);
      az = __builtin_amdgcn_mfma_f32_16x16x32_bf16(ah[c], whh1[c], az, 0, 0, 0);
      an = __builtin_amdgcn_mfma_f32_16x16x32_bf16(ah[c], whh2[c], an, 0, 0, 0);
    }
#pragma unroll
    for (int q = 0; q < 4; ++q) {
      float r = sigm(ar[q] + gr[q] + bias_r);
      float zz = sigm(az[q] + gz[q] + bias_z);
      float nn = tanhfast(gn[q] + bihn + r * (an[q] + bhhn));
      float hq = (1.0f - zz) * nn + zz * h[q];
      h[q] = hq;
      hbuf[nxt][SWZ(g4 * 4 + q, j)] = rne_bf16(hq);
    }
    __syncthreads();
  }
#pragma unroll
  for (int q = 0; q < 4; ++q) hfin[g4 * 4 + q][j] = h[q];
  __syncthreads();
  float s = 0.0f;
#pragma unroll
  for (int i = 0; i < 4; ++i) {
    int k = lane + 64 * i;
    s += hfin[w][k] * Wout[k];
  }
#pragma unroll
  for (int off = 32; off > 0; off >>= 1) s += __shfl_xor(s, off, 64);
  if (lane == 0) out[b0 + w] = sigm(s + bout[0]);
}

extern "C" void kernel_launch(void* const* d_in, const int* in_sizes, int n_in,
                              void* d_out, int out_size, void* d_ws, size_t ws_size,
                              hipStream_t stream) {
  const float* x    = (const float*)d_in[0];
  const float* Wih  = (const float*)d_in[1];
  const float* Whh  = (const float*)d_in[2];
  const float* bih  = (const float*)d_in[3];
  const float* bhh  = (const float*)d_in[4];
  const float* Wout = (const float*)d_in[5];
  const float* bout = (const float*)d_in[6];
  float* out = (float*)d_out;

  const size_t HBYTES = (size_t)BB * HH * sizeof(float);  // 256 KB h checkpoint
  const size_t STEP_BYTES = (size_t)16 * 512 * 48;        // 384 KB gi per step
  size_t gi_cap = ws_size > HBYTES ? ws_size - HBYTES : 0;
  long tc = (long)(gi_cap / STEP_BYTES);
  if (tc > TT) tc = TT;

  if (tc >= 32) {
    float* hchk = (float*)d_ws;
    unsigned short* gi = (unsigned short*)((char*)d_ws + HBYTES);
    for (int t0 = 0; t0 < TT; t0 += (int)tc) {
      int nt = (TT - t0) < (int)tc ? (TT - t0) : (int)tc;
      gi_gemm8<<<dim3(256), dim3(512), 0, stream>>>(
          x + (size_t)t0 * BB * II, Wih, bih, bhh, gi, nt * 16);
      gru_step7<<<dim3(16), dim3(512), 0, stream>>>(
          Whh, bhh, Wout, bout, gi, hchk, out, t0, nt);
    }
  } else {
    gru_fused_legacy<<<dim3(16), dim3(1024), 0, stream>>>(
        x, Wih, Whh, bih, bhh, Wout, bout, out);
  }
}

// Round 10
// 924.706 us; speedup vs baseline: 1.4725x; 1.4725x over previous
//
#include <hip/hip_runtime.h>
#include <hip/hip_bf16.h>

// GRU forward, T=512 B=256 I=H=256 fp32 in, fp32 [B,1] out.
// v10: compiler-allocated AGPR pinning (the sound version of v8/v9).
//  - r,z gate weights: 32 x short8 = EXACTLY 128 regs, pinned into AGPR
//    *class* via one-time `asm("" : "+a"(w))`. The allocator chooses which
//    AGPRs (no collision with its own values, unlike v9's hard-coded a0-127).
//    Step MFMAs read srcB in-place from AGPR ("a" constraint; per-operand ACC
//    bits, ISA §10). AGPR writes happen ONLY at init, fenced by s_nop 7 x2
//    and a __syncthreads before first use. Nothing writes AGPRs in the loop.
//  - n gate streams from LDS (v2-verified fragment layout, 16B/lane
//    conflict-free reads; LDS pipe overlaps the MFMA pipe).
//  - arch working set ~90 <= 128; 128 arch + 128 AGPR = 256 = 2 waves/EU.
//  - combine math, packed-bf16 h, gi layout, gi_gemm8: v7-verbatim (v7
//    PASSED at absmax 0.0039; only its all-"v" register demand was wrong).

#define TT 512
#define BB 256
#define II 256
#define HH 256

#define SRZ (-1.4426950408889634f)   // -log2(e): sigmoid(a) = rcp(1+exp2(SRZ*a))
#define SN  (2.8853900817779268f)    // 2*log2(e): tanh(y) = 1-2*rcp(1+exp2(SN*y))

typedef __attribute__((ext_vector_type(8))) short short8;
typedef __attribute__((ext_vector_type(4))) float f32x4;

__device__ __forceinline__ unsigned short rne_bf16(float f) {
  union { float f; unsigned u; } v; v.f = f;
  unsigned r = v.u + 0x7FFFu + ((v.u >> 16) & 1u);
  return (unsigned short)(r >> 16);
}
__device__ __forceinline__ float bf2f(unsigned short b) {
  union { unsigned u; float f; } v; v.u = ((unsigned)b) << 16;
  return v.f;
}
__device__ __forceinline__ float blo(unsigned p) {
  union { unsigned u; float f; } v; v.u = p << 16; return v.f;
}
__device__ __forceinline__ float bhi(unsigned p) {
  union { unsigned u; float f; } v; v.u = p & 0xffff0000u; return v.f;
}
__device__ __forceinline__ float sigm(float x) { return 1.0f / (1.0f + __expf(-x)); }
__device__ __forceinline__ float tanhfast(float x) {
  return 1.0f - 2.0f / (__expf(2.0f * x) + 1.0f);
}

__device__ __forceinline__ short8 ldw8(const float* __restrict__ p) {
  float4 a = *reinterpret_cast<const float4*>(p);
  float4 b = *reinterpret_cast<const float4*>(p + 4);
  short8 r;
  r[0] = (short)rne_bf16(a.x); r[1] = (short)rne_bf16(a.y);
  r[2] = (short)rne_bf16(a.z); r[3] = (short)rne_bf16(a.w);
  r[4] = (short)rne_bf16(b.x); r[5] = (short)rne_bf16(b.y);
  r[6] = (short)rne_bf16(b.z); r[7] = (short)rne_bf16(b.w);
  return r;
}
__device__ __forceinline__ short8 ldw8s(const float* __restrict__ p, float s) {
  float4 a = *reinterpret_cast<const float4*>(p);
  float4 b = *reinterpret_cast<const float4*>(p + 4);
  short8 r;
  r[0] = (short)rne_bf16(a.x * s); r[1] = (short)rne_bf16(a.y * s);
  r[2] = (short)rne_bf16(a.z * s); r[3] = (short)rne_bf16(a.w * s);
  r[4] = (short)rne_bf16(b.x * s); r[5] = (short)rne_bf16(b.y * s);
  r[6] = (short)rne_bf16(b.z * s); r[7] = (short)rne_bf16(b.w * s);
  return r;
}

// 8-elem-granule XOR swizzle for [16][256] ushort tiles
#define SWZ8(m, k) ((m) * 256 + ((k) ^ (((m) & 7) * 8)))
// legacy 16-granule swizzle (fallback kernel only)
#define SWZ(m, k) ((m) * 256 + ((k) ^ ((m) * 16)))

// ---- AGPR-class pinning & MFMA helpers -------------------------------------
// One-time: force w into an AGPR-class virtual register (allocator picks which
// physical AGPRs). Subsequent "a"-constrained uses read it in place, no copies.
__device__ __forceinline__ void pin_agpr(short8& w) {
  asm volatile("" : "+a"(w));
}
// MFMA, B operand in AGPR (weights), A/C/D in arch VGPRs.
__device__ __forceinline__ void mfma_ag(f32x4& d, short8 a, const short8& b) {
  asm volatile("v_mfma_f32_16x16x32_bf16 %0, %1, %2, %0"
               : "+v"(d) : "v"(a), "a"(b));
}
__device__ __forceinline__ void mfma_ag_f(f32x4& d, short8 a, const short8& b) {
  asm volatile("s_nop 1\n\tv_mfma_f32_16x16x32_bf16 %0, %1, %2, %0"
               : "+v"(d) : "v"(a), "a"(b));
}
// MFMA, B operand in VGPR (n-gate streamed from LDS).
__device__ __forceinline__ void mfma_v(f32x4& d, short8 a, short8 b) {
  asm volatile("v_mfma_f32_16x16x32_bf16 %0, %1, %2, %0"
               : "+v"(d) : "v"(a), "v"(b));
}
__device__ __forceinline__ void mfma_v_f(f32x4& d, short8 a, short8 b) {
  asm volatile("s_nop 1\n\tv_mfma_f32_16x16x32_bf16 %0, %1, %2, %0"
               : "+v"(d) : "v"(a), "v"(b));
}
__device__ __forceinline__ void mfma_fence6(f32x4& a0, f32x4& a1, f32x4& a2,
                                            f32x4& a3, f32x4& a4, f32x4& a5) {
  asm volatile("s_nop 7\n\ts_nop 7"
               : "+v"(a0), "+v"(a1), "+v"(a2), "+v"(a3), "+v"(a4), "+v"(a5));
}
__device__ __forceinline__ unsigned cvtpk_bf16(float lo, float hi) {
  unsigned r;
  asm("v_cvt_pk_bf16_f32 %0, %1, %2" : "=v"(r) : "v"(lo), "v"(hi));
  return r;
}

// ---------------- Phase 1: gi = scale*(x @ W_ih^T + bias) -------------------
// (v7's gi_gemm8, verbatim — PASSED, ~85us)
// gi ushort layout: ((tile*8 + w)*64 + l)*24 + g*8 + ct*4 + q, tile = t*16+bx.
__global__ __launch_bounds__(512)
__attribute__((amdgpu_waves_per_eu(2, 2)))
void gi_gemm8(const float* __restrict__ x, const float* __restrict__ Wih,
              const float* __restrict__ bih, const float* __restrict__ bhh,
              unsigned short* __restrict__ gi, int ntiles) {
  __shared__ __align__(16) unsigned short ax[2][4096];
  const int tid = threadIdx.x, l = tid & 63, w = tid >> 6;
  const int g4 = l >> 4, i15 = l & 15;

  short8 wf[3][2][8];
  float bs[3][2];
#pragma unroll
  for (int g = 0; g < 3; ++g)
#pragma unroll
    for (int ct = 0; ct < 2; ++ct) {
      int j = 32 * w + 16 * ct + i15;
      float s = (g == 2) ? SN : SRZ;
#pragma unroll
      for (int c = 0; c < 8; ++c)
        wf[g][ct][c] = ldw8s(Wih + (size_t)(g * 256 + j) * 256 + c * 32 + g4 * 8, s);
      bs[g][ct] = (g == 2) ? SN * bih[512 + j]
                           : SRZ * (bih[g * 256 + j] + bhh[g * 256 + j]);
    }

  auto stage = [&](int buf, int t) {
#pragma unroll
    for (int p = 0; p < 2; ++p) {
      int idx = p * 512 + tid;
      int m = idx >> 6, k0 = (idx & 63) << 2;
      float4 v = *reinterpret_cast<const float4*>(x + (size_t)t * 4096 + m * 256 + k0);
      ushort4 b;
      b.x = rne_bf16(v.x); b.y = rne_bf16(v.y);
      b.z = rne_bf16(v.z); b.w = rne_bf16(v.w);
      *reinterpret_cast<ushort4*>(&ax[buf][SWZ8(m, k0)]) = b;
    }
  };

  if (blockIdx.x >= ntiles) return;
  stage(0, blockIdx.x);
  int cur = 0;
  for (int tile = blockIdx.x; tile < ntiles; tile += 256) {
    __syncthreads();
    int tn = tile + 256;
    if (tn < ntiles) stage(cur ^ 1, tn);
    f32x4 aR[2] = {{0, 0, 0, 0}, {0, 0, 0, 0}};
    f32x4 aZ[2] = {{0, 0, 0, 0}, {0, 0, 0, 0}};
    f32x4 aN[2] = {{0, 0, 0, 0}, {0, 0, 0, 0}};
#pragma unroll
    for (int c = 0; c < 8; ++c) {
      short8 ah = *reinterpret_cast<const short8*>(&ax[cur][SWZ8(l & 15, c * 32 + g4 * 8)]);
#pragma unroll
      for (int ct = 0; ct < 2; ++ct) {
        if (c == 0) {
          mfma_v_f(aR[ct], ah, wf[0][ct][0]);
          mfma_v_f(aZ[ct], ah, wf[1][ct][0]);
          mfma_v_f(aN[ct], ah, wf[2][ct][0]);
        } else {
          mfma_v(aR[ct], ah, wf[0][ct][c]);
          mfma_v(aZ[ct], ah, wf[1][ct][c]);
          mfma_v(aN[ct], ah, wf[2][ct][c]);
        }
      }
    }
    mfma_fence6(aR[0], aR[1], aZ[0], aZ[1], aN[0], aN[1]);
    unsigned short* gp = gi + ((size_t)tile * 512 + (size_t)(w * 64 + l)) * 24;
    short8 oR, oZ, oN;
#pragma unroll
    for (int ct = 0; ct < 2; ++ct)
#pragma unroll
      for (int q = 0; q < 4; ++q) {
        oR[ct * 4 + q] = (short)rne_bf16(aR[ct][q] + bs[0][ct]);
        oZ[ct * 4 + q] = (short)rne_bf16(aZ[ct][q] + bs[1][ct]);
        oN[ct * 4 + q] = (short)rne_bf16(aN[ct][q] + bs[2][ct]);
      }
    *reinterpret_cast<short8*>(gp) = oR;
    *reinterpret_cast<short8*>(gp + 8) = oZ;
    *reinterpret_cast<short8*>(gp + 16) = oN;
    cur ^= 1;
  }
}

// ---------------- Phase 2: persistent GRU recurrence (v10) ----------------
__global__ __launch_bounds__(512)
__attribute__((amdgpu_waves_per_eu(2, 2)))
void gru_step10(const float* __restrict__ Whh, const float* __restrict__ bhh,
                const float* __restrict__ Wout, const float* __restrict__ bout,
                const unsigned short* __restrict__ gi, float* __restrict__ hchk,
                float* __restrict__ out, int t0, int nt) {
  __shared__ __align__(16) unsigned char arena[147456];  // 144 KB
  unsigned short* ldsn = (unsigned short*)arena;                 // 128KB n-gate frags
  unsigned short* hbuf0 = (unsigned short*)(arena + 131072);     // 8KB
  unsigned short* hbuf1 = (unsigned short*)(arena + 139264);     // 8KB
  const int tid = threadIdx.x, l = tid & 63, w = tid >> 6;
  const int g4 = l >> 4, i15 = l & 15;
  const int bx = blockIdx.x, b0 = bx * 16;

  // r,z weights: 32 x short8 = exactly 128 regs, pinned to AGPR class.
  short8 wR[2][8], wZ[2][8];
#pragma unroll
  for (int ct = 0; ct < 2; ++ct) {
    int j = 32 * w + 16 * ct + i15;
#pragma unroll
    for (int c = 0; c < 8; ++c) {
      wR[ct][c] = ldw8s(Whh + (size_t)j * 256 + c * 32 + g4 * 8, SRZ);
      wZ[ct][c] = ldw8s(Whh + (size_t)(256 + j) * 256 + c * 32 + g4 * 8, SRZ);
      pin_agpr(wR[ct][c]);
      pin_agpr(wZ[ct][c]);
    }
  }
  asm volatile("s_nop 7\n\ts_nop 7" ::: "memory");  // accvgpr_write -> MFMA guard

  // n weights -> LDS fragment stream (v2-verified layout, conflict-free)
  float cn[2];
#pragma unroll
  for (int tl = 0; tl < 2; ++tl) {
    int j = 32 * w + 16 * tl + i15;
#pragma unroll
    for (int c = 0; c < 8; ++c) {
      short8 fn = ldw8s(Whh + (size_t)(512 + j) * 256 + c * 32 + g4 * 8, SN);
      *reinterpret_cast<short8*>(
          &ldsn[(size_t)(((w * 2 + tl) * 8 + c) * 64 + l) * 8]) = fn;
    }
    cn[tl] = SN * bhh[512 + j];
  }
  const unsigned short* nbase = ldsn + (size_t)l * 8 + (size_t)w * 8192;

  // h master: packed bf16 pairs (v7-verified)
  unsigned hp[2][2];
  if (t0 == 0) {
    hp[0][0] = hp[0][1] = hp[1][0] = hp[1][1] = 0;
    for (int i = tid; i < 4096; i += 512) hbuf0[i] = 0;
  } else {
#pragma unroll
    for (int ct = 0; ct < 2; ++ct) {
      int j = 32 * w + 16 * ct + i15;
      float v0 = hchk[(size_t)(b0 + 4 * g4 + 0) * 256 + j];
      float v1 = hchk[(size_t)(b0 + 4 * g4 + 1) * 256 + j];
      float v2 = hchk[(size_t)(b0 + 4 * g4 + 2) * 256 + j];
      float v3 = hchk[(size_t)(b0 + 4 * g4 + 3) * 256 + j];
      hp[ct][0] = cvtpk_bf16(v0, v1);
      hp[ct][1] = cvtpk_bf16(v2, v3);
      hbuf0[SWZ8(4 * g4 + 0, j)] = (unsigned short)hp[ct][0];
      hbuf0[SWZ8(4 * g4 + 1, j)] = (unsigned short)(hp[ct][0] >> 16);
      hbuf0[SWZ8(4 * g4 + 2, j)] = (unsigned short)hp[ct][1];
      hbuf0[SWZ8(4 * g4 + 3, j)] = (unsigned short)(hp[ct][1] >> 16);
    }
  }
  const unsigned short* gp = gi + ((size_t)(bx * 8 + w) * 64 + l) * 24;
  __syncthreads();

#pragma unroll 1
  for (int lt = 0; lt < nt; ++lt) {
    // this step's gi: 3 dwordx4, issued now, consumed post-fence
    short8 gR = *reinterpret_cast<const short8*>(gp);
    short8 gZ = *reinterpret_cast<const short8*>(gp + 8);
    short8 gN = *reinterpret_cast<const short8*>(gp + 16);

    f32x4 aR[2] = {{0, 0, 0, 0}, {0, 0, 0, 0}};
    f32x4 aZ[2] = {{0, 0, 0, 0}, {0, 0, 0, 0}};
    f32x4 aN[2] = {{0, 0, 0, 0}, {0, 0, 0, 0}};
    const unsigned short* hb = (lt & 1) ? hbuf1 : hbuf0;
    unsigned short* hw = (lt & 1) ? hbuf0 : hbuf1;
#pragma unroll
    for (int c = 0; c < 8; ++c) {
      short8 ah = *reinterpret_cast<const short8*>(&hb[SWZ8(l & 15, c * 32 + g4 * 8)]);
      short8 fn0 = *reinterpret_cast<const short8*>(nbase + c * 512);
      short8 fn1 = *reinterpret_cast<const short8*>(nbase + (8 + c) * 512);
      if (c == 0) {
        mfma_ag_f(aR[0], ah, wR[0][0]);
        mfma_ag_f(aR[1], ah, wR[1][0]);
        mfma_ag_f(aZ[0], ah, wZ[0][0]);
        mfma_ag_f(aZ[1], ah, wZ[1][0]);
        mfma_v_f(aN[0], ah, fn0);
        mfma_v_f(aN[1], ah, fn1);
      } else {
        mfma_ag(aR[0], ah, wR[0][c]);
        mfma_ag(aR[1], ah, wR[1][c]);
        mfma_ag(aZ[0], ah, wZ[0][c]);
        mfma_ag(aZ[1], ah, wZ[1][c]);
        mfma_v(aN[0], ah, fn0);
        mfma_v(aN[1], ah, fn1);
      }
    }
    mfma_fence6(aR[0], aR[1], aZ[0], aZ[1], aN[0], aN[1]);

#pragma unroll
    for (int ct = 0; ct < 2; ++ct) {
      int j = 32 * w + 16 * ct + i15;
      float hq[4];
#pragma unroll
      for (int q = 0; q < 4; ++q) {
        float hold = (q & 1) ? bhi(hp[ct][q >> 1]) : blo(hp[ct][q >> 1]);
        float rr = __builtin_amdgcn_rcpf(
            1.0f + __builtin_amdgcn_exp2f(aR[ct][q] + bf2f((unsigned short)gR[ct * 4 + q])));
        float zz = __builtin_amdgcn_rcpf(
            1.0f + __builtin_amdgcn_exp2f(aZ[ct][q] + bf2f((unsigned short)gZ[ct * 4 + q])));
        float y = bf2f((unsigned short)gN[ct * 4 + q]) + rr * (aN[ct][q] + cn[ct]);
        float nn = 1.0f - 2.0f * __builtin_amdgcn_rcpf(1.0f + __builtin_amdgcn_exp2f(y));
        hq[q] = nn + zz * (hold - nn);
      }
      hp[ct][0] = cvtpk_bf16(hq[0], hq[1]);
      hp[ct][1] = cvtpk_bf16(hq[2], hq[3]);
      hw[SWZ8(4 * g4 + 0, j)] = (unsigned short)hp[ct][0];
      hw[SWZ8(4 * g4 + 1, j)] = (unsigned short)(hp[ct][0] >> 16);
      hw[SWZ8(4 * g4 + 2, j)] = (unsigned short)hp[ct][1];
      hw[SWZ8(4 * g4 + 3, j)] = (unsigned short)(hp[ct][1] >> 16);
    }
    gp += 196608;
    __syncthreads();
  }

  if (t0 + nt < TT) {
#pragma unroll
    for (int ct = 0; ct < 2; ++ct) {
      int j = 32 * w + 16 * ct + i15;
      hchk[(size_t)(b0 + 4 * g4 + 0) * 256 + j] = blo(hp[ct][0]);
      hchk[(size_t)(b0 + 4 * g4 + 1) * 256 + j] = bhi(hp[ct][0]);
      hchk[(size_t)(b0 + 4 * g4 + 2) * 256 + j] = blo(hp[ct][1]);
      hchk[(size_t)(b0 + 4 * g4 + 3) * 256 + j] = bhi(hp[ct][1]);
    }
  } else {
    // overlay hfin on ldsn (n-weights dead; loop's final barrier protects)
    float* hfin = (float*)arena;
#pragma unroll
    for (int ct = 0; ct < 2; ++ct) {
      int j = 32 * w + 16 * ct + i15;
      hfin[(4 * g4 + 0) * 256 + j] = blo(hp[ct][0]);
      hfin[(4 * g4 + 1) * 256 + j] = bhi(hp[ct][0]);
      hfin[(4 * g4 + 2) * 256 + j] = blo(hp[ct][1]);
      hfin[(4 * g4 + 3) * 256 + j] = bhi(hp[ct][1]);
    }
    __syncthreads();
#pragma unroll
    for (int rr = 0; rr < 2; ++rr) {
      int r = 2 * w + rr;
      float s = 0.0f;
#pragma unroll
      for (int k = 0; k < 4; ++k) {
        int col = l + 64 * k;
        s += hfin[r * 256 + col] * Wout[col];
      }
#pragma unroll
      for (int off = 32; off > 0; off >>= 1) s += __shfl_xor(s, off, 64);
      if (l == 0) out[b0 + r] = sigm(s + bout[0]);
    }
  }
}

// ---------------- Fused fallback (used only if ws too small) ------------
__global__ __launch_bounds__(1024, 1) void gru_fused_legacy(
    const float* __restrict__ x, const float* __restrict__ Wih,
    const float* __restrict__ Whh, const float* __restrict__ bih,
    const float* __restrict__ bhh, const float* __restrict__ Wout,
    const float* __restrict__ bout, float* __restrict__ out) {
  __shared__ unsigned short hbuf[2][16 * 256];
  __shared__ unsigned short xbuf[2][16 * 256];
  __shared__ float hfin[16][256];
  int tid = threadIdx.x, lane = tid & 63, w = tid >> 6;
  int i15 = lane & 15, g4 = lane >> 4;
  int b0 = blockIdx.x * 16;
  int j = 16 * w + i15;

  short8 whh0[8], whh1[8], whh2[8], wih0[8], wih1[8], wih2[8];
#pragma unroll
  for (int c = 0; c < 8; ++c) {
    int ko = c * 32 + g4 * 8;
    whh0[c] = ldw8(Whh + (size_t)j * 256 + ko);
    whh1[c] = ldw8(Whh + (size_t)(256 + j) * 256 + ko);
    whh2[c] = ldw8(Whh + (size_t)(512 + j) * 256 + ko);
    wih0[c] = ldw8(Wih + (size_t)j * 256 + ko);
    wih1[c] = ldw8(Wih + (size_t)(256 + j) * 256 + ko);
    wih2[c] = ldw8(Wih + (size_t)(512 + j) * 256 + ko);
  }
  float bias_r = bih[j] + bhh[j];
  float bias_z = bih[256 + j] + bhh[256 + j];
  float bihn = bih[512 + j], bhhn = bhh[512 + j];

  f32x4 h = {0, 0, 0, 0};
  for (int idx = tid; idx < 16 * 256; idx += 1024) hbuf[0][idx] = 0;
  {
    int m = tid >> 6, k0 = (tid & 63) << 2;
    float4 v = *reinterpret_cast<const float4*>(x + (size_t)b0 * II + m * 256 + k0);
    ushort4 b;
    b.x = rne_bf16(v.x); b.y = rne_bf16(v.y);
    b.z = rne_bf16(v.z); b.w = rne_bf16(v.w);
    *reinterpret_cast<ushort4*>(&xbuf[0][SWZ(m, k0)]) = b;
  }
  __syncthreads();

  for (int lt = 0; lt < TT; ++lt) {
    int cur = lt & 1, nxt = cur ^ 1;
    short8 ah[8], axf[8];
#pragma unroll
    for (int c = 0; c < 8; ++c) {
      int m = lane & 15, k0 = c * 32 + g4 * 8;
      ah[c] = *reinterpret_cast<const short8*>(&hbuf[cur][SWZ(m, k0)]);
      axf[c] = *reinterpret_cast<const short8*>(&xbuf[cur][SWZ(m, k0)]);
    }
    f32x4 gr = {0, 0, 0, 0}, gz = {0, 0, 0, 0}, gn = {0, 0, 0, 0};
    f32x4 ar = {0, 0, 0, 0}, az = {0, 0, 0, 0}, an = {0, 0, 0, 0};
#pragma unroll
    for (int c = 0; c < 8; ++c) {
      gr = __builtin_amdgcn_mfma_f32_16x16x32_bf16(axf[c], wih0[c], gr, 0, 0, 0);
      gz = __builtin_amdgcn_mfma_f32_16x16x32_bf16(axf[c], wih1[c], gz, 0, 0, 0);
      gn = __builtin_amdgcn_mfma_f32_16x16x32_bf16(axf[c], wih2[c], gn, 0, 0, 0);
    }
    if (lt + 1 < TT) {
      int m = tid >> 6, k0 = (tid & 63) << 2;
      float4 v = *reinterpret_cast<const float4*>(
          x + ((size_t)(lt + 1) * BB + b0) * II + m * 256 + k0);
      ushort4 b;
      b.x = rne_bf16(v.x); b.y = rne_bf16(v.y);
      b.z = rne_bf16(v.z); b.w = rne_bf16(v.w);
      *reinterpret_cast<ushort4*>(&xbuf[nxt][SWZ(m, k0)]) = b;
    }
#pragma unroll
    for (int c = 0; c < 8; ++c) {
      ar = __builtin_amdgcn_mfma_f32_16x16x32_bf16(ah[c], whh0[c], ar, 0, 0, 0);
      az = __builtin_amdgcn_mfma_f32_16x16x32_bf16(ah[c], whh1[c], az, 0, 0, 0);
      an = __builtin_amdgcn_mfma_f32_16x16x32_bf16(ah[c], whh2[c], an, 0, 0, 0);
    }
#pragma unroll
    for (int q = 0; q < 4; ++q) {
      float r = sigm(ar[q] + gr[q] + bias_r);
      float zz = sigm(az[q] + gz[q] + bias_z);
      float nn = tanhfast(gn[q] + bihn + r * (an[q] + bhhn));
      float hq = (1.0f - zz) * nn + zz * h[q];
      h[q] = hq;
      hbuf[nxt][SWZ(g4 * 4 + q, j)] = rne_bf16(hq);
    }
    __syncthreads();
  }
#pragma unroll
  for (int q = 0; q < 4; ++q) hfin[g4 * 4 + q][j] = h[q];
  __syncthreads();
  float s = 0.0f;
#pragma unroll
  for (int i = 0; i < 4; ++i) {
    int k = lane + 64 * i;
    s += hfin[w][k] * Wout[k];
  }
#pragma unroll
  for (int off = 32; off > 0; off >>= 1) s += __shfl_xor(s, off, 64);
  if (lane == 0) out[b0 + w] = sigm(s + bout[0]);
}

extern "C" void kernel_launch(void* const* d_in, const int* in_sizes, int n_in,
                              void* d_out, int out_size, void* d_ws, size_t ws_size,
                              hipStream_t stream) {
  const float* x    = (const float*)d_in[0];
  const float* Wih  = (const float*)d_in[1];
  const float* Whh  = (const float*)d_in[2];
  const float* bih  = (const float*)d_in[3];
  const float* bhh  = (const float*)d_in[4];
  const float* Wout = (const float*)d_in[5];
  const float* bout = (const float*)d_in[6];
  float* out = (float*)d_out;

  const size_t HBYTES = (size_t)BB * HH * sizeof(float);  // 256 KB h checkpoint
  const size_t STEP_BYTES = (size_t)16 * 512 * 48;        // 384 KB gi per step
  size_t gi_cap = ws_size > HBYTES ? ws_size - HBYTES : 0;
  long tc = (long)(gi_cap / STEP_BYTES);
  if (tc > TT) tc = TT;

  if (tc >= 32) {
    float* hchk = (float*)d_ws;
    unsigned short* gi = (unsigned short*)((char*)d_ws + HBYTES);
    for (int t0 = 0; t0 < TT; t0 += (int)tc) {
      int nt = (TT - t0) < (int)tc ? (TT - t0) : (int)tc;
      gi_gemm8<<<dim3(256), dim3(512), 0, stream>>>(
          x + (size_t)t0 * BB * II, Wih, bih, bhh, gi, nt * 16);
      gru_step10<<<dim3(16), dim3(512), 0, stream>>>(
          Whh, bhh, Wout, bout, gi, hchk, out, t0, nt);
    }
  } else {
    gru_fused_legacy<<<dim3(16), dim3(1024), 0, stream>>>(
        x, Wih, Whh, bih, bhh, Wout, bout, out);
  }
}